// Round 4
// baseline (400.967 us; speedup 1.0000x reference)
//
#include <hip/hip_runtime.h>
#include <hip/hip_cooperative_groups.h>

namespace cg = cooperative_groups;

#define BB 64
#define SS 2048
#define DD 128
#define DDV 256
#define NCH 32          // S / 64 chunks for PV
#define RPC 64          // rows per chunk
#define NBLK 1024       // cooperative grid: 4 blocks/CU guaranteed by launch_bounds(256,4)
#define RPB 128         // phase-1 rows per block (B*S / NBLK)
#define RPW 32          // phase-1 rows per wave

// tanh(x) = 1 - 2/(e^{2x}+1). __expf -> v_exp_f32; div is rcp+refine (~4 instr).
// ~8 VALU instrs vs ~20 for tanhf; error ~1e-6, output threshold is 7e-3.
__device__ __forceinline__ float fast_tanh(float x) {
    const float t = __expf(2.0f * x);
    return 1.0f - 2.0f / (t + 1.0f);
}

__global__ __launch_bounds__(256, 4) void k_fused(
    const float* __restrict__ q, const float* __restrict__ k,
    const float* __restrict__ values, const int* __restrict__ valid,
    const float* __restrict__ wv,
    float* __restrict__ blend, float4* __restrict__ stats,
    float* __restrict__ partial, float* __restrict__ out)
{
    cg::grid_group grid = cg::this_grid();
    const int t    = threadIdx.x;
    const int wid  = t >> 6;
    const int lane = t & 63;
    const int blk  = blockIdx.x;

    __shared__ float4 sacc[256];   // P3 cross-wave reduce
    __shared__ float  sred[4];     // P2 cross-wave reduce
    __shared__ float  wsm[RPC];    // P3 weights

    // ---------------- Phase 1: blend[row] = 0.5*scores1 + 0.5 ----------------
    // Wave per row; lanes 0-31 take q, 32-63 take k; one float4 each.
    {
        const float* src = (lane < 32) ? q : k;
        const float4 w4  = *(const float4*)(wv + lane * 4);
        const int row0   = blk * RPB + wid * RPW;
#pragma unroll 4
        for (int i = 0; i < RPW; ++i) {
            const int row  = row0 + i;
            const float4 x = *(const float4*)(src + (size_t)row * DD + (lane & 31) * 4);
            float acc = fast_tanh(x.x) * w4.x + fast_tanh(x.y) * w4.y
                      + fast_tanh(x.z) * w4.z + fast_tanh(x.w) * w4.w;
#pragma unroll
            for (int o = 32; o; o >>= 1) acc += __shfl_xor(acc, o, 64);
            if (lane == 0) blend[row] = 0.5f * acc + 0.5f;
        }
    }
    grid.sync();

    // ---------------- Phase 2: per-batch softmax stats (blocks 0..63) ----------------
    // stats[b] = (m1, 1/Z1, m2, 1/Z2); weights recomputed inline in phase 3.
    if (blk < BB) {
        const float* rowp = blend + (size_t)blk * SS;
        float v[8];
#pragma unroll
        for (int i = 0; i < 8; ++i) v[i] = rowp[t + i * 256];

        float m = v[0];
#pragma unroll
        for (int i = 1; i < 8; ++i) m = fmaxf(m, v[i]);
#pragma unroll
        for (int o = 32; o; o >>= 1) m = fmaxf(m, __shfl_xor(m, o, 64));
        if (lane == 0) sred[wid] = m;
        __syncthreads();
        const float m1 = fmaxf(fmaxf(sred[0], sred[1]), fmaxf(sred[2], sred[3]));
        __syncthreads();

        float e[8]; float s = 0.f;
#pragma unroll
        for (int i = 0; i < 8; ++i) { e[i] = expf(v[i] - m1); s += e[i]; }
#pragma unroll
        for (int o = 32; o; o >>= 1) s += __shfl_xor(s, o, 64);
        if (lane == 0) sred[wid] = s;
        __syncthreads();
        const float Z1 = sred[0] + sred[1] + sred[2] + sred[3];
        __syncthreads();
        const float invZ1 = 1.f / Z1;

        const int L = valid[blk];
        float mm = -1e30f;
#pragma unroll
        for (int i = 0; i < 8; ++i) {
            if (t + i * 256 < L) mm = fmaxf(mm, e[i] * invZ1);
        }
#pragma unroll
        for (int o = 32; o; o >>= 1) mm = fmaxf(mm, __shfl_xor(mm, o, 64));
        if (lane == 0) sred[wid] = mm;
        __syncthreads();
        const float m2 = fmaxf(fmaxf(sred[0], sred[1]), fmaxf(sred[2], sred[3]));
        __syncthreads();

        float s2 = 0.f;
#pragma unroll
        for (int i = 0; i < 8; ++i) {
            if (t + i * 256 < L) s2 += expf(e[i] * invZ1 - m2);
        }
#pragma unroll
        for (int o = 32; o; o >>= 1) s2 += __shfl_xor(s2, o, 64);
        if (lane == 0) sred[wid] = s2;
        __syncthreads();
        const float Z2 = sred[0] + sred[1] + sred[2] + sred[3];
        if (t == 0) stats[blk] = make_float4(m1, invZ1, m2, 1.f / Z2);
    }
    grid.sync();

    // ---------------- Phase 3: PV partials (grid-stride over B*NCH tasks) ----------------
    for (int task = blk; task < BB * NCH; task += NBLK) {
        const int b  = task >> 5;          // NCH = 32
        const int c  = task & (NCH - 1);
        const int s0 = c * RPC;
        const int L  = valid[b];
        float4 acc = {0.f, 0.f, 0.f, 0.f};
        if (s0 < L) {
            const float4 st = stats[b];
            if (t < RPC) {
                const int s = s0 + t;
                float w = 0.f;
                if (s < L)   // same expression order as phase 2 -> bitwise identical
                    w = expf(expf(blend[(size_t)b * SS + s] - st.x) * st.y - st.z) * st.w;
                wsm[t] = w;
            }
            __syncthreads();
            float wr[16]; bool any = false;
#pragma unroll
            for (int i = 0; i < 16; ++i) { wr[i] = wsm[wid * 16 + i]; any |= (wr[i] != 0.f); }
            if (any) {
                const float* vb = values + ((size_t)b * SS + s0 + wid * 16) * DDV + lane * 4;
#pragma unroll
                for (int i = 0; i < 16; ++i) {
                    const float4 v4 = *(const float4*)(vb + (size_t)i * DDV);
                    acc.x += wr[i] * v4.x; acc.y += wr[i] * v4.y;
                    acc.z += wr[i] * v4.z; acc.w += wr[i] * v4.w;
                }
            }
            __syncthreads();
        }
        sacc[t] = acc;
        __syncthreads();
        if (t < 64) {
            const float4 a0 = sacc[t], a1 = sacc[t + 64], a2 = sacc[t + 128], a3 = sacc[t + 192];
            float4 r;
            r.x = a0.x + a1.x + a2.x + a3.x;
            r.y = a0.y + a1.y + a2.y + a3.y;
            r.z = a0.z + a1.z + a2.z + a3.z;
            r.w = a0.w + a1.w + a2.w + a3.w;
            *(float4*)(partial + ((size_t)(b * NCH + c)) * 256 + t * 4) = r;
        }
        __syncthreads();
    }
    grid.sync();

    // ---------------- Phase 4: reduce partials -> out (blocks 0..63) ----------------
    if (blk < BB) {
        float a = 0.f;
#pragma unroll
        for (int c = 0; c < NCH; ++c)
            a += partial[((size_t)blk * NCH + c) * 256 + t];
        out[(size_t)blk * 256 + t] = a;
    }
}

extern "C" void kernel_launch(void* const* d_in, const int* in_sizes, int n_in,
                              void* d_out, int out_size, void* d_ws, size_t ws_size,
                              hipStream_t stream) {
    const float* q    = (const float*)d_in[0];
    const float* k    = (const float*)d_in[1];
    const float* v    = (const float*)d_in[2];
    const int*   vlen = (const int*)d_in[3];
    const float* wv   = (const float*)d_in[4];
    // d_in[5..7] (w2, w_v2_w, w_v2_b) are dead: softmax over singleton axis == 1.

    float*  blend   = (float*)d_ws;                       // B*S floats      (512 KB)
    float4* stats   = (float4*)(blend + (size_t)BB * SS); // B float4        (1 KB)
    float*  partial = (float*)(stats + BB);               // B*NCH*256 float (2 MB)
    float*  out     = (float*)d_out;

    void* args[] = { (void*)&q, (void*)&k, (void*)&v, (void*)&vlen, (void*)&wv,
                     (void*)&blend, (void*)&stats, (void*)&partial, (void*)&out };
    hipLaunchCooperativeKernel((const void*)k_fused, dim3(NBLK), dim3(256), args, 0, stream);
}

// Round 5
// 46.533 us; speedup vs baseline: 8.6169x; 8.6169x over previous
//
#include <hip/hip_runtime.h>

#define BB 64
#define SS 2048
#define DD 128
#define DDV 256
#define NCH 32          // S / 64 chunks for PV
#define RPC 64          // rows per chunk

// tanh(x) = 1 - 2/(e^{2x}+1). __expf -> v_exp_f32; ~8 VALU instrs vs ~20 for
// tanhf. Verified in round 4: absmax 7.6e-6 vs 7.1e-3 threshold.
__device__ __forceinline__ float fast_tanh(float x) {
    const float t = __expf(2.0f * x);
    return 1.0f - 2.0f / (t + 1.0f);
}

// ---------------- Kernel 1: blend[b*S+s] = 0.5*scores1 + 0.5 ----------------
// 4 waves/block, 4 rows/wave -> 16 rows/block, 8192 blocks. Lanes 0-31 take
// the q half, 32-63 the k half; one float4 per lane per row. wv index is
// wv[lane*4] for both halves (first 128 weights q, next 128 k).
__global__ __launch_bounds__(256) void k_blend(const float* __restrict__ q,
                                               const float* __restrict__ k,
                                               const float* __restrict__ wv,
                                               float* __restrict__ blend) {
    const int wave = threadIdx.x >> 6;
    const int lane = threadIdx.x & 63;
    const float* src = (lane < 32) ? q : k;
    const float4 w4  = *(const float4*)(wv + lane * 4);
    const int row0 = blockIdx.x * 16 + wave * 4;
#pragma unroll
    for (int i = 0; i < 4; ++i) {
        const int row  = row0 + i;
        const float4 x = *(const float4*)(src + (size_t)row * DD + (lane & 31) * 4);
        float acc = fast_tanh(x.x) * w4.x + fast_tanh(x.y) * w4.y
                  + fast_tanh(x.z) * w4.z + fast_tanh(x.w) * w4.w;
#pragma unroll
        for (int o = 32; o; o >>= 1) acc += __shfl_xor(acc, o, 64);
        if (lane == 0) blend[row] = 0.5f * acc + 0.5f;
    }
}

// ---------------- Kernel 2: double softmax -> attention weights ----------------
// One block of 1024 per batch; 2 elements/thread in registers; wave butterfly
// + 16-entry LDS combine; 4 barriers total. Writes weights in-place over
// blend (exact 0 for s >= valid_len).
__global__ __launch_bounds__(1024) void k_weights(float* __restrict__ blend,
                                                  const int* __restrict__ valid) {
    __shared__ float r0[16], r1[16], r2[16], r3[16];
    const int b = blockIdx.x;
    const int t = threadIdx.x;
    const int wid = t >> 6, lane = t & 63;
    float* rowp = blend + (size_t)b * SS;

    const float v0 = rowp[t];
    const float v1 = rowp[t + 1024];

    float m = fmaxf(v0, v1);
#pragma unroll
    for (int o = 32; o; o >>= 1) m = fmaxf(m, __shfl_xor(m, o, 64));
    if (lane == 0) r0[wid] = m;
    __syncthreads();
    float m1 = r0[0];
#pragma unroll
    for (int i = 1; i < 16; i++) m1 = fmaxf(m1, r0[i]);

    const float e0 = expf(v0 - m1), e1 = expf(v1 - m1);
    float s = e0 + e1;
#pragma unroll
    for (int o = 32; o; o >>= 1) s += __shfl_xor(s, o, 64);
    if (lane == 0) r1[wid] = s;
    __syncthreads();
    float Z1 = 0.f;
#pragma unroll
    for (int i = 0; i < 16; i++) Z1 += r1[i];
    const float invZ1 = 1.f / Z1;
    const float p0 = e0 * invZ1, p1 = e1 * invZ1;

    const int L = valid[b];

    float mm = -1e30f;
    if (t < L)        mm = p0;
    if (t + 1024 < L) mm = fmaxf(mm, p1);
#pragma unroll
    for (int o = 32; o; o >>= 1) mm = fmaxf(mm, __shfl_xor(mm, o, 64));
    if (lane == 0) r2[wid] = mm;
    __syncthreads();
    float m2 = r2[0];
#pragma unroll
    for (int i = 1; i < 16; i++) m2 = fmaxf(m2, r2[i]);

    const float f0 = (t < L)        ? expf(p0 - m2) : 0.f;
    const float f1 = (t + 1024 < L) ? expf(p1 - m2) : 0.f;
    float s2 = f0 + f1;
#pragma unroll
    for (int o = 32; o; o >>= 1) s2 += __shfl_xor(s2, o, 64);
    if (lane == 0) r3[wid] = s2;
    __syncthreads();
    float Z2 = 0.f;
#pragma unroll
    for (int i = 0; i < 16; i++) Z2 += r3[i];
    const float invZ2 = 1.f / Z2;

    rowp[t]        = f0 * invZ2;
    rowp[t + 1024] = f1 * invZ2;
}

// ---------------- Kernel 3: partial PV sums ----------------
// grid (NCH, B), 256 threads. Wave w owns rows [w*16, w*16+16); each lane
// owns a float4 column slice -> 16 unrolled unconditional float4 loads,
// predicated by weight VALUE (not by load). Block early-outs (writing a zero
// partial) when the whole chunk is past valid_len.
__global__ __launch_bounds__(256) void k_pv(const float* __restrict__ w,
                                            const float* __restrict__ values,
                                            const int* __restrict__ valid,
                                            float* __restrict__ partial) {
    const int c = blockIdx.x, b = blockIdx.y;
    const int t = threadIdx.x;
    const int wid = t >> 6, lane = t & 63;
    const int s0 = c * RPC;
    __shared__ float wsm[RPC];
    __shared__ float4 sacc[256];

    const int L = valid[b];
    float4 acc = {0.f, 0.f, 0.f, 0.f};
    if (s0 < L) {
        if (t < RPC) wsm[t] = w[(size_t)b * SS + s0 + t];
        __syncthreads();
        float wr[16];
        bool any = false;
#pragma unroll
        for (int i = 0; i < 16; i++) { wr[i] = wsm[wid * 16 + i]; any |= (wr[i] != 0.f); }
        if (any) {
            const float* vb = values + ((size_t)b * SS + s0 + wid * 16) * DDV + lane * 4;
#pragma unroll
            for (int i = 0; i < 16; i++) {
                const float4 v4 = *(const float4*)(vb + (size_t)i * DDV);
                acc.x += wr[i] * v4.x;
                acc.y += wr[i] * v4.y;
                acc.z += wr[i] * v4.z;
                acc.w += wr[i] * v4.w;
            }
        }
    }
    sacc[t] = acc;
    __syncthreads();
    if (t < 64) {
        const float4 a0 = sacc[t], a1 = sacc[t + 64], a2 = sacc[t + 128], a3 = sacc[t + 192];
        float4 r;
        r.x = a0.x + a1.x + a2.x + a3.x;
        r.y = a0.y + a1.y + a2.y + a3.y;
        r.z = a0.z + a1.z + a2.z + a3.z;
        r.w = a0.w + a1.w + a2.w + a3.w;
        *(float4*)(partial + ((size_t)(b * NCH + c)) * 256 + t * 4) = r;
    }
}

// ---------------- Kernel 4: reduce partials -> out ----------------
__global__ __launch_bounds__(256) void k_reduce(const float* __restrict__ partial,
                                                float* __restrict__ out) {
    const int b = blockIdx.x, t = threadIdx.x;
    float acc = 0.f;
#pragma unroll
    for (int c = 0; c < NCH; c++) acc += partial[((size_t)b * NCH + c) * 256 + t];
    out[(size_t)b * 256 + t] = acc;
}

extern "C" void kernel_launch(void* const* d_in, const int* in_sizes, int n_in,
                              void* d_out, int out_size, void* d_ws, size_t ws_size,
                              hipStream_t stream) {
    const float* q    = (const float*)d_in[0];
    const float* k    = (const float*)d_in[1];
    const float* v    = (const float*)d_in[2];
    const int*   vlen = (const int*)d_in[3];
    const float* wv   = (const float*)d_in[4];
    // d_in[5..7] (w2, w_v2_w, w_v2_b) are dead: softmax over singleton axis == 1.

    float* blend   = (float*)d_ws;                 // B*S floats        (512 KB)
    float* partial = blend + (size_t)BB * SS;      // B*NCH*256 floats  (2 MB)
    float* out     = (float*)d_out;

    k_blend <<<dim3(BB * SS / 16), dim3(256),  0, stream>>>(q, k, wv, blend);
    k_weights<<<dim3(BB),          dim3(1024), 0, stream>>>(blend, vlen);
    k_pv     <<<dim3(NCH, BB),     dim3(256),  0, stream>>>(blend, v, vlen, partial);
    k_reduce <<<dim3(BB),          dim3(256),  0, stream>>>(partial, out);
}

// Round 6
// 45.216 us; speedup vs baseline: 8.8678x; 1.0291x over previous
//
#include <hip/hip_runtime.h>

#define BB 64
#define SS 2048
#define DD 128
#define DDV 256
#define NCH 32          // S / 64 chunks for PV
#define RPC 64          // rows per chunk

// tanh(x) = 1 - 2/(e^{2x}+1) with raw v_rcp_f32 (no IEEE refine).
// |rel err| ~1e-7 vs 7.1e-3 output threshold.
__device__ __forceinline__ float fast_tanh(float x) {
    const float t = __expf(2.0f * x);
    return 1.0f - 2.0f * __builtin_amdgcn_rcpf(t + 1.0f);
}

// ---------------- Kernel 1: blend[b*S+s] = 0.5*scores1 ----------------
// (+0.5 shift dropped: cancels in softmax #1. 0.5 scale folded into w4.)
// 4 waves/block, 8 rows/wave -> 32 rows/block, 4096 blocks. Lanes 0-31 take
// the q half, 32-63 the k half; one float4 per lane per row.
__global__ __launch_bounds__(256) void k_blend(const float* __restrict__ q,
                                               const float* __restrict__ k,
                                               const float* __restrict__ wv,
                                               float* __restrict__ blend) {
    const int wave = threadIdx.x >> 6;
    const int lane = threadIdx.x & 63;
    const float* src = (lane < 32) ? q : k;
    float4 w4 = *(const float4*)(wv + lane * 4);
    w4.x *= 0.5f; w4.y *= 0.5f; w4.z *= 0.5f; w4.w *= 0.5f;
    const int row0 = blockIdx.x * 32 + wave * 8;
    const float* base = src + (size_t)row0 * DD + (lane & 31) * 4;
#pragma unroll
    for (int i = 0; i < 8; ++i) {
        const float4 x = *(const float4*)(base + (size_t)i * DD);
        float acc = fast_tanh(x.x) * w4.x + fast_tanh(x.y) * w4.y
                  + fast_tanh(x.z) * w4.z + fast_tanh(x.w) * w4.w;
#pragma unroll
        for (int o = 32; o; o >>= 1) acc += __shfl_xor(acc, o, 64);
        if (lane == 0) blend[row0 + i] = acc;
    }
}

// ---------------- Kernel 2: per-batch softmax stats ----------------
// One block of 1024 per batch; 2 elements/thread in registers; wave butterfly
// + 16-entry LDS combine; 4 barriers. stats[b] = (m1, 1/Z1, m2, 1/Z2).
// No weight writeback — k_pv recomputes weights inline.
__global__ __launch_bounds__(1024) void k_stats(const float* __restrict__ blend,
                                                const int* __restrict__ valid,
                                                float4* __restrict__ stats) {
    __shared__ float r0[16], r1[16], r2[16], r3[16];
    const int b = blockIdx.x;
    const int t = threadIdx.x;
    const int wid = t >> 6, lane = t & 63;
    const float* rowp = blend + (size_t)b * SS;

    const float v0 = rowp[t];
    const float v1 = rowp[t + 1024];

    float m = fmaxf(v0, v1);
#pragma unroll
    for (int o = 32; o; o >>= 1) m = fmaxf(m, __shfl_xor(m, o, 64));
    if (lane == 0) r0[wid] = m;
    __syncthreads();
    float m1 = r0[0];
#pragma unroll
    for (int i = 1; i < 16; i++) m1 = fmaxf(m1, r0[i]);

    const float e0 = expf(v0 - m1), e1 = expf(v1 - m1);
    float s = e0 + e1;
#pragma unroll
    for (int o = 32; o; o >>= 1) s += __shfl_xor(s, o, 64);
    if (lane == 0) r1[wid] = s;
    __syncthreads();
    float Z1 = 0.f;
#pragma unroll
    for (int i = 0; i < 16; i++) Z1 += r1[i];
    const float invZ1 = 1.f / Z1;

    const int L = valid[b];

    float mm = -1e30f;
    if (t < L)        mm = e0 * invZ1;
    if (t + 1024 < L) mm = fmaxf(mm, e1 * invZ1);
#pragma unroll
    for (int o = 32; o; o >>= 1) mm = fmaxf(mm, __shfl_xor(mm, o, 64));
    if (lane == 0) r2[wid] = mm;
    __syncthreads();
    float m2 = r2[0];
#pragma unroll
    for (int i = 1; i < 16; i++) m2 = fmaxf(m2, r2[i]);

    float s2 = 0.f;
    if (t < L)        s2  = expf(e0 * invZ1 - m2);
    if (t + 1024 < L) s2 += expf(e1 * invZ1 - m2);
#pragma unroll
    for (int o = 32; o; o >>= 1) s2 += __shfl_xor(s2, o, 64);
    if (lane == 0) r3[wid] = s2;
    __syncthreads();
    float Z2 = 0.f;
#pragma unroll
    for (int i = 0; i < 16; i++) Z2 += r3[i];
    if (t == 0) stats[b] = make_float4(m1, invZ1, m2, 1.f / Z2);
}

// ---------------- Kernel 3: partial PV sums ----------------
// grid (NCH, B), 256 threads. Weights recomputed inline from blend + stats.
// Wave w owns rows [w*16, w*16+16); each lane owns a float4 column slice ->
// 16 unrolled unconditional float4 loads, predicated by weight value.
// Block early-outs (writing a zero partial) when chunk is past valid_len.
__global__ __launch_bounds__(256) void k_pv(const float* __restrict__ blend,
                                            const float4* __restrict__ stats,
                                            const float* __restrict__ values,
                                            const int* __restrict__ valid,
                                            float* __restrict__ partial) {
    const int c = blockIdx.x, b = blockIdx.y;
    const int t = threadIdx.x;
    const int wid = t >> 6, lane = t & 63;
    const int s0 = c * RPC;
    __shared__ float wsm[RPC];
    __shared__ float4 sacc[256];

    const int L = valid[b];
    float4 acc = {0.f, 0.f, 0.f, 0.f};
    if (s0 < L) {
        const float4 st = stats[b];
        if (t < RPC) {
            const int s = s0 + t;
            float w = 0.f;
            if (s < L)
                w = expf(expf(blend[(size_t)b * SS + s] - st.x) * st.y - st.z) * st.w;
            wsm[t] = w;
        }
        __syncthreads();
        float wr[16];
        bool any = false;
#pragma unroll
        for (int i = 0; i < 16; i++) { wr[i] = wsm[wid * 16 + i]; any |= (wr[i] != 0.f); }
        if (any) {
            const float* vb = values + ((size_t)b * SS + s0 + wid * 16) * DDV + lane * 4;
#pragma unroll
            for (int i = 0; i < 16; i++) {
                const float4 v4 = *(const float4*)(vb + (size_t)i * DDV);
                acc.x += wr[i] * v4.x;
                acc.y += wr[i] * v4.y;
                acc.z += wr[i] * v4.z;
                acc.w += wr[i] * v4.w;
            }
        }
    }
    sacc[t] = acc;
    __syncthreads();
    if (t < 64) {
        const float4 a0 = sacc[t], a1 = sacc[t + 64], a2 = sacc[t + 128], a3 = sacc[t + 192];
        float4 r;
        r.x = a0.x + a1.x + a2.x + a3.x;
        r.y = a0.y + a1.y + a2.y + a3.y;
        r.z = a0.z + a1.z + a2.z + a3.z;
        r.w = a0.w + a1.w + a2.w + a3.w;
        *(float4*)(partial + ((size_t)(b * NCH + c)) * 256 + t * 4) = r;
    }
}

// ---------------- Kernel 4: reduce partials -> out ----------------
__global__ __launch_bounds__(256) void k_reduce(const float* __restrict__ partial,
                                                float* __restrict__ out) {
    const int b = blockIdx.x, t = threadIdx.x;
    float acc = 0.f;
#pragma unroll
    for (int c = 0; c < NCH; c++) acc += partial[((size_t)b * NCH + c) * 256 + t];
    out[(size_t)b * 256 + t] = acc;
}

extern "C" void kernel_launch(void* const* d_in, const int* in_sizes, int n_in,
                              void* d_out, int out_size, void* d_ws, size_t ws_size,
                              hipStream_t stream) {
    const float* q    = (const float*)d_in[0];
    const float* k    = (const float*)d_in[1];
    const float* v    = (const float*)d_in[2];
    const int*   vlen = (const int*)d_in[3];
    const float* wv   = (const float*)d_in[4];
    // d_in[5..7] (w2, w_v2_w, w_v2_b) are dead: softmax over singleton axis == 1.

    float*  blend   = (float*)d_ws;                       // B*S floats      (512 KB)
    float4* stats   = (float4*)(blend + (size_t)BB * SS); // B float4        (1 KB)
    float*  partial = (float*)(stats + BB);               // B*NCH*256 float (2 MB)
    float*  out     = (float*)d_out;

    k_blend <<<dim3(BB * SS / 32), dim3(256),  0, stream>>>(q, k, wv, blend);
    k_stats <<<dim3(BB),           dim3(1024), 0, stream>>>(blend, vlen, stats);
    k_pv    <<<dim3(NCH, BB),      dim3(256),  0, stream>>>(blend, stats, v, vlen, partial);
    k_reduce<<<dim3(BB),           dim3(256),  0, stream>>>(partial, out);
}